// Round 16
// baseline (608.967 us; speedup 1.0000x reference)
//
#include <hip/hip_runtime.h>

typedef unsigned short u16;
typedef __attribute__((ext_vector_type(4))) float f32x4;
typedef __attribute__((ext_vector_type(8))) short s16x8;   // MFMA bf16 frag (8 bf16)
typedef __attribute__((ext_vector_type(8))) unsigned short u16x8;
typedef __attribute__((ext_vector_type(4))) unsigned short u16x4;

__device__ inline float bf2f(u16 u) {
    unsigned v = ((unsigned)u) << 16;
    return __builtin_bit_cast(float, v);
}
__device__ inline u16 f2bf(float f) {
    unsigned u = __builtin_bit_cast(unsigned, f);
    unsigned r = (u + 0x7FFFu + ((u >> 16) & 1u)) >> 16;
    return (u16)r;
}

// ---------------- CSR build ----------------
__global__ void count_kernel(const int* __restrict__ dst, int E, int* __restrict__ counts) {
    int e = blockIdx.x * 256 + threadIdx.x;
    if (e < E) atomicAdd(&counts[dst[e]], 1);
}

__global__ __launch_bounds__(1024) void scan_kernel(const int* __restrict__ counts,
    int* __restrict__ row_start, int* __restrict__ cursor, int NN) {
    __shared__ int sh[1024];
    const int tid = threadIdx.x;
    const int CH = (NN + 1023) / 1024;
    const int base = tid * CH;
    int sum = 0;
    for (int i = 0; i < CH; ++i) { int idx = base + i; if (idx < NN) sum += counts[idx]; }
    sh[tid] = sum; __syncthreads();
    for (int off = 1; off < 1024; off <<= 1) {
        int v = (tid >= off) ? sh[tid - off] : 0;
        __syncthreads();
        sh[tid] += v;
        __syncthreads();
    }
    int run = sh[tid] - sum;  // exclusive prefix
    for (int i = 0; i < CH; ++i) {
        int idx = base + i;
        if (idx <= NN) {
            row_start[idx] = run;
            if (idx < NN) { cursor[idx] = run; run += counts[idx]; }
        }
    }
}

__global__ void pos_kernel(const int* __restrict__ src, const int* __restrict__ dst, int E,
    int* __restrict__ cursor, int* __restrict__ pos, int* __restrict__ src_perm) {
    int e = blockIdx.x * 256 + threadIdx.x;
    if (e < E) {
        int p = atomicAdd(&cursor[dst[e]], 1);
        pos[e] = p;
        src_perm[p] = src[e];
    }
}

// ---------------- degree sort (descending), two-level: LDS hist -> few global atomics ----------------
__global__ __launch_bounds__(256) void deg_hist_kernel(const int* __restrict__ counts, int NN,
                                                       int* __restrict__ hist) {
    __shared__ int lh[1024];
    const int t = threadIdx.x;
    for (int i = t; i < 1024; i += 256) lh[i] = 0;
    __syncthreads();
    int n = blockIdx.x * 256 + t;
    if (n < NN) {
        int d = counts[n];
        int b = (d > 1023) ? 0 : (1023 - d);   // descending degree order
        atomicAdd(&lh[b], 1);
    }
    __syncthreads();
    for (int i = t; i < 1024; i += 256) {
        int c = lh[i];
        if (c) atomicAdd(&hist[i], c);
    }
}

__global__ __launch_bounds__(1024) void scan_hist_kernel(const int* __restrict__ hist,
                                                         int* __restrict__ hcur) {
    __shared__ int sh[1024];
    const int t = threadIdx.x;
    const int own = hist[t];
    sh[t] = own; __syncthreads();
    for (int off = 1; off < 1024; off <<= 1) {
        int v = (t >= off) ? sh[t - off] : 0;
        __syncthreads();
        sh[t] += v;
        __syncthreads();
    }
    hcur[t] = sh[t] - own;   // exclusive prefix
}

__global__ __launch_bounds__(256) void sort_fill_kernel(const int* __restrict__ counts, int NN,
                                 int* __restrict__ hcur, int* __restrict__ sorted) {
    __shared__ int lh[1024];     // local counts -> local rank source
    __shared__ int lbase[1024];  // block's global base per bin
    const int t = threadIdx.x;
    for (int i = t; i < 1024; i += 256) lh[i] = 0;
    __syncthreads();
    int n = blockIdx.x * 256 + t;
    int b = 0, lr = 0;
    const bool valid = n < NN;
    if (valid) {
        int d = counts[n];
        b = (d > 1023) ? 0 : (1023 - d);
        lr = atomicAdd(&lh[b], 1);         // local rank within block+bin (LDS, fast)
    }
    __syncthreads();
    for (int i = t; i < 1024; i += 256) {
        int c = lh[i];
        lbase[i] = c ? atomicAdd(&hcur[i], c) : 0;   // one global atomic per non-empty bin
    }
    __syncthreads();
    if (valid) sorted[lbase[b] + lr] = n;
}

// ---------------- fused setup: permute_pad_eattr + prep(x,Wa,Wet) + W1/W2 transpose ----------------
// Wet layout: [256 cols][32 k]; k<16 = We[k][col], k==16 = be[col], k>16 = 0
// eap layout: [E][32] bf16, dst-sorted, with bf16(1.0) marker at k=16
__global__ __launch_bounds__(256) void setup_fused_kernel(
    const float* __restrict__ ea, const int* __restrict__ pos, int E, int eb,
    const float* __restrict__ x, const float* __restrict__ Wa,
    const float* __restrict__ We, const float* __restrict__ be, int NN, int prepb,
    const float* __restrict__ W1, const float* __restrict__ W2,
    u16* __restrict__ eap_out, u16* __restrict__ x_bf, u16* __restrict__ Wat,
    u16* __restrict__ Wet, u16* __restrict__ W1t, u16* __restrict__ W2t) {
    __shared__ float T[32][33];
    const int b = blockIdx.x;
    if (b < eb) {
        // --- permute edge_attr into dst-sorted order, bf16, padded K 16->32 ---
        int e = b * 256 + threadIdx.x;
        if (e >= E) return;
        const float* r = ea + (size_t)e * 16;
        f32x4 q0 = *(const f32x4*)(r + 0);
        f32x4 q1 = *(const f32x4*)(r + 4);
        f32x4 q2 = *(const f32x4*)(r + 8);
        f32x4 q3 = *(const f32x4*)(r + 12);
        u16x8 v0, v1, m, z;
#pragma unroll
        for (int j = 0; j < 4; ++j) {
            v0[j] = f2bf(q0[j]); v0[4 + j] = f2bf(q1[j]);
            v1[j] = f2bf(q2[j]); v1[4 + j] = f2bf(q3[j]);
            m[j] = 0; m[4 + j] = 0; z[j] = 0; z[4 + j] = 0;
        }
        m[0] = 0x3F80;  // bf16(1.0) -> multiplies the be row of Wet
        u16* o = eap_out + (size_t)pos[e] * 32;
        *(u16x8*)(o + 0) = v0;
        *(u16x8*)(o + 8) = v1;
        *(u16x8*)(o + 16) = m;
        *(u16x8*)(o + 24) = z;
        return;
    }
    if (b < eb + prepb) {
        // --- x -> bf16; Wa -> Wat [256n][64k]; We/be -> Wet [256n][32k] ---
        int i = (b - eb) * 256 + threadIdx.x;
        const int S0 = NN * 16;  // x as vec4
        if (i < S0) {
            f32x4 v = *(const f32x4*)(x + (size_t)i * 4);
            u16x4 o; o.x = f2bf(v[0]); o.y = f2bf(v[1]); o.z = f2bf(v[2]); o.w = f2bf(v[3]);
            *(u16x4*)(x_bf + (size_t)i * 4) = o;
            return;
        }
        i -= S0;
        if (i < 16384) { int n = i >> 6, k = i & 63; Wat[i] = f2bf(Wa[k * 256 + n]); return; }
        i -= 16384;
        if (i < 8192) {
            int n = i >> 5, k = i & 31;
            float v = (k < 16) ? We[k * 256 + n] : ((k == 16) ? be[n] : 0.f);
            Wet[i] = f2bf(v);
        }
        return;
    }
    // --- LDS-tiled transpose of W1/W2: Wt[l][n][k] = W[l][k][n] ---
    const int bb = b - eb - prepb;            // 0..639
    const int m5 = bb >> 6;                   // 0..9
    const int rem = bb & 63;
    const int k0 = (rem & 7) * 32, n0 = (rem >> 3) * 32;
    const float* srcw = (m5 < 5) ? (W1 + (size_t)m5 * 65536) : (W2 + (size_t)(m5 - 5) * 65536);
    u16* dstw = (m5 < 5) ? (W1t + (size_t)m5 * 65536) : (W2t + (size_t)(m5 - 5) * 65536);
    const int tx = threadIdx.x & 31, ty = threadIdx.x >> 5;  // 32 x 8
#pragma unroll
    for (int i = 0; i < 4; ++i)
        T[ty + 8 * i][tx] = srcw[(size_t)(k0 + ty + 8 * i) * 256 + n0 + tx];
    __syncthreads();
#pragma unroll
    for (int i = 0; i < 4; ++i)
        dstw[(size_t)(n0 + ty + 8 * i) * 256 + k0 + tx] = f2bf(T[tx][ty + 8 * i]);
}

// ---------------- MFMA GEMM (f32 + bf16 out, used for h0) ----------------
__global__ __launch_bounds__(256) void gemm_h0_kernel(
    const u16* __restrict__ A, int lda, int M,
    const u16* __restrict__ Bt, int K,
    const float* __restrict__ bias,
    float* __restrict__ outF, u16* __restrict__ outB, int ldo) {
    __shared__ u16 As[128 * 32];
    __shared__ u16 Bs[128 * 32];
    const int tid = threadIdx.x, lane = tid & 63, wave = tid >> 6;
    const int m0 = blockIdx.x * 128, n0 = blockIdx.y * 128;
    const int wr = (wave >> 1) * 64, wc = (wave & 1) * 64;

    const f32x4 zero4 = {0.f, 0.f, 0.f, 0.f};
    f32x4 acc[4][4];
#pragma unroll
    for (int m = 0; m < 4; ++m)
#pragma unroll
        for (int n = 0; n < 4; ++n) acc[m][n] = zero4;

    for (int k0 = 0; k0 < K; k0 += 32) {
#pragma unroll
        for (int i = 0; i < 2; ++i) {
            int seg = i * 256 + tid;
            int row = seg >> 2, sk = seg & 3;
            int gr = m0 + row; gr = gr < M ? gr : M - 1;
            u16x8 va = *(const u16x8*)(A + (size_t)gr * lda + k0 + sk * 8);
            *(u16x8*)(&As[row * 32 + sk * 8]) = va;
            u16x8 vb = *(const u16x8*)(Bt + (size_t)(n0 + row) * K + k0 + sk * 8);
            *(u16x8*)(&Bs[row * 32 + sk * 8]) = vb;
        }
        __syncthreads();
        const int rsel = lane & 15, koff = (lane >> 4) * 8;
        s16x8 af[4], bf[4];
#pragma unroll
        for (int m = 0; m < 4; ++m) af[m] = *(const s16x8*)(&As[(wr + m * 16 + rsel) * 32 + koff]);
#pragma unroll
        for (int n = 0; n < 4; ++n) bf[n] = *(const s16x8*)(&Bs[(wc + n * 16 + rsel) * 32 + koff]);
#pragma unroll
        for (int m = 0; m < 4; ++m)
#pragma unroll
            for (int n = 0; n < 4; ++n)
                acc[m][n] = __builtin_amdgcn_mfma_f32_16x16x32_bf16(af[m], bf[n], acc[m][n], 0, 0, 0);
        __syncthreads();
    }

    const int cl = lane & 15, rq = lane >> 4;
#pragma unroll
    for (int n = 0; n < 4; ++n) {
        const int gcol = n0 + wc + n * 16 + cl;
        const float bv = bias[gcol];
#pragma unroll
        for (int m = 0; m < 4; ++m) {
#pragma unroll
            for (int j = 0; j < 4; ++j) {
                int grow = m0 + wr + m * 16 + rq * 4 + j;
                if (grow < M) {
                    float v = acc[m][n][j] + bv;
                    outF[(size_t)grow * ldo + gcol] = v;
                    outB[(size_t)grow * ldo + gcol] = f2bf(v);
                }
            }
        }
    }
}

// ---------------- fused MLP: y2 = relu(z@W1+b1)@W2+b2, with BN col stats ----------------
__global__ __launch_bounds__(256) void mlp_fused_kernel(
    const u16* __restrict__ z, int M,
    const u16* __restrict__ W1t, const float* __restrict__ b1,
    const u16* __restrict__ W2t, const float* __restrict__ b2,
    u16* __restrict__ y2,
    float* __restrict__ colsum, float* __restrict__ colsumsq) {
    __shared__ u16 As[64 * 32];     // 4 KB
    __shared__ u16 Bs[256 * 32];    // 16 KB
    __shared__ u16 Ys[64 * 260];    // 33.3 KB
    const int tid = threadIdx.x, lane = tid & 63, wave = tid >> 6;
    const int m0 = blockIdx.x * 64;
    const int wc = wave * 64;
    const int rsel = lane & 15, koff = (lane >> 4) * 8;
    const int cl = lane & 15, rq = lane >> 4;

    const f32x4 zero4 = {0.f, 0.f, 0.f, 0.f};
    f32x4 acc[4][4];
#pragma unroll
    for (int m = 0; m < 4; ++m)
#pragma unroll
        for (int n = 0; n < 4; ++n) acc[m][n] = zero4;

    // ---- phase 1: y1 = z @ W1 ----
    for (int k0 = 0; k0 < 256; k0 += 32) {
        {
            int row = tid >> 2, sk = tid & 3;
            int gr = m0 + row; gr = gr < M ? gr : M - 1;
            u16x8 va = *(const u16x8*)(z + (size_t)gr * 256 + k0 + sk * 8);
            *(u16x8*)(&As[row * 32 + sk * 8]) = va;
        }
#pragma unroll
        for (int i = 0; i < 4; ++i) {
            int seg = i * 256 + tid;
            int row = seg >> 2, sk = seg & 3;
            u16x8 vb = *(const u16x8*)(W1t + (size_t)row * 256 + k0 + sk * 8);
            *(u16x8*)(&Bs[row * 32 + sk * 8]) = vb;
        }
        __syncthreads();
        s16x8 af[4], bf[4];
#pragma unroll
        for (int m = 0; m < 4; ++m) af[m] = *(const s16x8*)(&As[(m * 16 + rsel) * 32 + koff]);
#pragma unroll
        for (int n = 0; n < 4; ++n) bf[n] = *(const s16x8*)(&Bs[(wc + n * 16 + rsel) * 32 + koff]);
#pragma unroll
        for (int m = 0; m < 4; ++m)
#pragma unroll
            for (int n = 0; n < 4; ++n)
                acc[m][n] = __builtin_amdgcn_mfma_f32_16x16x32_bf16(af[m], bf[n], acc[m][n], 0, 0, 0);
        __syncthreads();
    }
    // epilogue 1: relu(y1 + b1) -> Ys
#pragma unroll
    for (int n = 0; n < 4; ++n) {
        const int gcol = wc + n * 16 + cl;
        const float bv = b1[gcol];
#pragma unroll
        for (int m = 0; m < 4; ++m) {
#pragma unroll
            for (int j = 0; j < 4; ++j) {
                int row = m * 16 + rq * 4 + j;
                float v = fmaxf(acc[m][n][j] + bv, 0.f);
                Ys[row * 260 + gcol] = f2bf(v);
            }
        }
        acc[0][n] = zero4; acc[1][n] = zero4; acc[2][n] = zero4; acc[3][n] = zero4;
    }

    // ---- phase 2: y2 = relu_y1 @ W2 ----
    for (int k0 = 0; k0 < 256; k0 += 32) {
#pragma unroll
        for (int i = 0; i < 4; ++i) {
            int seg = i * 256 + tid;
            int row = seg >> 2, sk = seg & 3;
            u16x8 vb = *(const u16x8*)(W2t + (size_t)row * 256 + k0 + sk * 8);
            *(u16x8*)(&Bs[row * 32 + sk * 8]) = vb;
        }
        __syncthreads();
        s16x8 af[4], bf[4];
#pragma unroll
        for (int m = 0; m < 4; ++m) af[m] = *(const s16x8*)(&Ys[(m * 16 + rsel) * 260 + k0 + koff]);
#pragma unroll
        for (int n = 0; n < 4; ++n) bf[n] = *(const s16x8*)(&Bs[(wc + n * 16 + rsel) * 32 + koff]);
#pragma unroll
        for (int m = 0; m < 4; ++m)
#pragma unroll
            for (int n = 0; n < 4; ++n)
                acc[m][n] = __builtin_amdgcn_mfma_f32_16x16x32_bf16(af[m], bf[n], acc[m][n], 0, 0, 0);
        __syncthreads();
    }
    // epilogue 2: stats + stage into Ys, then coalesced write
#pragma unroll
    for (int n = 0; n < 4; ++n) {
        const int gcol = wc + n * 16 + cl;
        const float bv = b2[gcol];
        float s = 0.f, ss = 0.f;
#pragma unroll
        for (int m = 0; m < 4; ++m) {
#pragma unroll
            for (int j = 0; j < 4; ++j) {
                int row = m * 16 + rq * 4 + j;
                float v = acc[m][n][j] + bv;
                Ys[row * 260 + gcol] = f2bf(v);
                if (m0 + row < M) { s += v; ss += v * v; }
            }
        }
        s += __shfl_down(s, 32); ss += __shfl_down(ss, 32);
        s += __shfl_down(s, 16); ss += __shfl_down(ss, 16);
        if (rq == 0) {
            atomicAdd(&colsum[gcol], s);
            atomicAdd(&colsumsq[gcol], ss);
        }
    }
    __syncthreads();
    for (int r0 = 0; r0 < 64; r0 += 8) {
        int row = r0 + (tid >> 5);
        int gr = m0 + row;
        int cc = (tid & 31) * 8;
        if (gr < M) *(u16x8*)(y2 + (size_t)gr * 256 + cc) = *(u16x8*)(&Ys[row * 260 + cc]);
    }
}

// ---------------- aggregation: MFMA edge-projection into wave-private LDS tile,
// then coalesced accumulate. 2-wave blocks (16.9 KB LDS -> 9 blocks/CU) +
// degree-sorted node order: minimal block-exit waste. No __syncthreads. ----------------
__global__ __launch_bounds__(128) void agg_rc_kernel(
    const int* __restrict__ sorted_nodes,
    const int* __restrict__ row_start, const int* __restrict__ src_perm,
    const u16* __restrict__ eap, const u16* __restrict__ Wet,
    const u16* __restrict__ h_bf,
    const float* __restrict__ eps, int layer,
    u16* __restrict__ z_bf, int NN) {
    __shared__ u16 ET[2 * 16 * 264];   // 16.9 KB: 2 waves x (16 edges x 264-stride bf16)
    const int tid = threadIdx.x;
    const int lane = tid & 63;
    const int wv = tid >> 6;
    const int rsel = lane & 15;
    const int q = lane >> 4;
    const int half = lane >> 5;
    const int c0 = (lane & 31) * 8;
    u16* et = &ET[wv * 16 * 264];

    // Wet A-fragments in registers: lane holds Wet[b*16+rsel][q*8..+7] for each col-block b
    s16x8 wf[16];
#pragma unroll
    for (int b = 0; b < 16; ++b)
        wf[b] = *(const s16x8*)(Wet + (b * 16 + rsel) * 32 + q * 8);

    const int idx = blockIdx.x * 2 + wv;
    if (idx >= NN) return;
    const int node = sorted_nodes[idx];
    const int s0 = row_start[node], s1 = row_start[node + 1];

    const f32x4 zero4 = {0.f, 0.f, 0.f, 0.f};
    float a[8] = {0.f, 0.f, 0.f, 0.f, 0.f, 0.f, 0.f, 0.f};

    for (int e0 = s0; e0 < s1; e0 += 16) {
        // --- project 16 edges: e = ea @ We + be, D[col][edge] -> LDS tile ---
        const int ec = (e0 + rsel < s1) ? (e0 + rsel) : (s1 - 1);
        s16x8 eaf = *(const s16x8*)(eap + (size_t)ec * 32 + q * 8);
#pragma unroll
        for (int b = 0; b < 16; ++b) {
            f32x4 d = __builtin_amdgcn_mfma_f32_16x16x32_bf16(wf[b], eaf, zero4, 0, 0, 0);
            u16x4 w;
#pragma unroll
            for (int j = 0; j < 4; ++j) w[j] = f2bf(d[j]);
            *(u16x4*)(et + rsel * 264 + b * 16 + q * 4) = w;   // lane owns edge=rsel, cols b*16+q*4..+3
        }
        // --- accumulate: half-wave per edge, 16B loads, 4 edges in flight ---
        const int cnt = (s1 - e0 < 16) ? (s1 - e0) : 16;
        for (int kk = 0; kk < cnt; kk += 4) {
            const int ka = kk + half, kb = kk + 2 + half;
            const bool v0 = ka < cnt, v1 = kb < cnt;
            const int ia = v0 ? (e0 + ka) : (s1 - 1);
            const int ib = v1 ? (e0 + kb) : (s1 - 1);
            const int sa = src_perm[ia];
            const int sb = src_perm[ib];
            u16x8 h0 = *(const u16x8*)(h_bf + (size_t)sa * 256 + c0);
            u16x8 h1 = *(const u16x8*)(h_bf + (size_t)sb * 256 + c0);
            u16x8 e8a = *(const u16x8*)(et + (v0 ? ka : 0) * 264 + c0);
            u16x8 e8b = *(const u16x8*)(et + (v1 ? kb : 0) * 264 + c0);
            const float m0 = v0 ? 1.f : 0.f;
            const float m1 = v1 ? 1.f : 0.f;
#pragma unroll
            for (int j = 0; j < 8; ++j) {
                a[j] += m0 * fmaxf(bf2f((u16)e8a[j]) + bf2f((u16)h0[j]), 0.f);
                a[j] += m1 * fmaxf(bf2f((u16)e8b[j]) + bf2f((u16)h1[j]), 0.f);
            }
        }
    }
#pragma unroll
    for (int j = 0; j < 8; ++j) a[j] += __shfl_xor(a[j], 32);
    if (half == 0) {
        const float c = 1.f + eps[layer];
        u16x8 hbv = *(const u16x8*)(h_bf + (size_t)node * 256 + c0);
        u16x8 z;
#pragma unroll
        for (int j = 0; j < 8; ++j)
            z[j] = f2bf(c * bf2f((u16)hbv[j]) + a[j]);
        *(u16x8*)(z_bf + (size_t)node * 256 + c0) = z;
    }
}

// ---------------- BN + relu + residual (8 elements/thread) ----------------
__global__ __launch_bounds__(256) void bn_res_kernel(
    const u16* __restrict__ y2, const float* __restrict__ colsum,
    const float* __restrict__ colsumsq, const float* __restrict__ gamma,
    const float* __restrict__ beta, const float* __restrict__ hin,
    float* __restrict__ hout, u16* __restrict__ h_bf, int write_bf,
    float invN, int total8) {
    const int i = blockIdx.x * 256 + threadIdx.x;
    if (i >= total8) return;
    const size_t base = (size_t)i * 8;
    const int c0 = (int)(base & 255);
    u16x8 yv = *(const u16x8*)(y2 + base);
    f32x4 hv0 = *(const f32x4*)(hin + base);
    f32x4 hv1 = *(const f32x4*)(hin + base + 4);
    float res[8];
#pragma unroll
    for (int j = 0; j < 8; ++j) {
        const int c = c0 + j;
        const float mu = colsum[c] * invN;
        const float var = colsumsq[c] * invN - mu * mu;
        const float sc = gamma[c] * rsqrtf(var + 1e-5f);
        const float sh = beta[c] - mu * sc;
        float v = bf2f((u16)yv[j]) * sc + sh;
        v = fmaxf(v, 0.f);
        res[j] = ((j < 4) ? hv0[j] : hv1[j - 4]) + v;
    }
    f32x4 o0, o1;
#pragma unroll
    for (int j = 0; j < 4; ++j) { o0[j] = res[j]; o1[j] = res[4 + j]; }
    *(f32x4*)(hout + base) = o0;
    *(f32x4*)(hout + base + 4) = o1;
    if (write_bf) {
        u16x8 hb;
#pragma unroll
        for (int j = 0; j < 8; ++j) hb[j] = f2bf(res[j]);
        *(u16x8*)(h_bf + base) = hb;
    }
}

extern "C" void kernel_launch(void* const* d_in, const int* in_sizes, int n_in,
                              void* d_out, int out_size, void* d_ws, size_t ws_size,
                              hipStream_t stream) {
    const float* x    = (const float*)d_in[0];
    const float* ea   = (const float*)d_in[1];
    const int*   ei   = (const int*)d_in[2];
    const float* Wa   = (const float*)d_in[3];
    const float* ba   = (const float*)d_in[4];
    const float* We   = (const float*)d_in[5];
    const float* be   = (const float*)d_in[6];
    const float* eps  = (const float*)d_in[7];
    const float* W1   = (const float*)d_in[8];
    const float* b1   = (const float*)d_in[9];
    const float* W2   = (const float*)d_in[10];
    const float* b2   = (const float*)d_in[11];
    const float* gamma= (const float*)d_in[12];
    const float* beta = (const float*)d_in[13];

    const int NN = in_sizes[0] / 64;
    const int EE = in_sizes[1] / 16;
    const int* src = ei;
    const int* dst = ei + EE;

    char* p = (char*)d_ws;
    auto alloc = [&](size_t bytes) -> char* {
        char* r = p;
        p += (bytes + 255) & ~(size_t)255;
        return r;
    };
    int*   counts   = (int*)alloc((size_t)(NN + 1) * 4);   // zeroed region start
    float* colsum   = (float*)alloc(5 * 256 * 4);
    float* colsumsq = (float*)alloc(5 * 256 * 4);
    int*   hist     = (int*)alloc(1024 * 4);
    size_t zbytes   = (size_t)(p - (char*)counts);
    int*   hcur     = (int*)alloc(1024 * 4);
    int*   sorted   = (int*)alloc((size_t)NN * 4);
    int*   row_start= (int*)alloc((size_t)(NN + 1) * 4);
    int*   cursor   = (int*)alloc((size_t)NN * 4);
    int*   pos      = (int*)alloc((size_t)EE * 4);
    int*   src_perm = (int*)alloc((size_t)EE * 4);
    u16*   x_bf     = (u16*)alloc((size_t)NN * 64 * 2);
    u16*   Wat      = (u16*)alloc(256 * 64 * 2);
    u16*   Wet      = (u16*)alloc(256 * 32 * 2);
    u16*   W1t      = (u16*)alloc((size_t)5 * 65536 * 2);
    u16*   W2t      = (u16*)alloc((size_t)5 * 65536 * 2);
    u16*   eap_perm = (u16*)alloc((size_t)EE * 32 * 2);
    float* h        = (float*)alloc((size_t)NN * 256 * 4);
    u16*   h_bf     = (u16*)alloc((size_t)NN * 256 * 2);
    u16*   z_bf     = (u16*)alloc((size_t)NN * 256 * 2);
    u16*   y2       = (u16*)alloc((size_t)NN * 256 * 2);

    hipMemsetAsync(counts, 0, zbytes, stream);

    const int eb = (EE + 255) / 256;
    const int nb = (NN + 255) / 256;
    count_kernel<<<eb, 256, 0, stream>>>(dst, EE, counts);
    scan_kernel<<<1, 1024, 0, stream>>>(counts, row_start, cursor, NN);
    pos_kernel<<<eb, 256, 0, stream>>>(src, dst, EE, cursor, pos, src_perm);

    // degree sort (descending) for agg block balance -- two-level, low-contention
    deg_hist_kernel<<<nb, 256, 0, stream>>>(counts, NN, hist);
    scan_hist_kernel<<<1, 1024, 0, stream>>>(hist, hcur);
    sort_fill_kernel<<<nb, 256, 0, stream>>>(counts, NN, hcur, sorted);

    const int prep_total = NN * 16 + 16384 + 8192;
    const int prepb = (prep_total + 255) / 256;
    const int setup_blocks = eb + prepb + 640;
    setup_fused_kernel<<<setup_blocks, 256, 0, stream>>>(
        ea, pos, EE, eb, x, Wa, We, be, NN, prepb, W1, W2,
        eap_perm, x_bf, Wat, Wet, W1t, W2t);

    // h0 = x @ Wa + ba  -> h (f32) and h_bf (bf16)
    dim3 gh((NN + 127) / 128, 2);
    gemm_h0_kernel<<<gh, 256, 0, stream>>>(
        x_bf, 64, NN, Wat, 64, ba, h, h_bf, 256);

    const float invN = 1.f / (float)NN;
    const int nb8 = (NN * 32 + 255) / 256;
    const int mlp_blocks = (NN + 63) / 64;
    for (int l = 0; l < 5; ++l) {
        agg_rc_kernel<<<(NN + 1) / 2, 128, 0, stream>>>(
            sorted, row_start, src_perm, eap_perm, Wet, h_bf, eps, l, z_bf, NN);
        mlp_fused_kernel<<<mlp_blocks, 256, 0, stream>>>(
            z_bf, NN, W1t + (size_t)l * 65536, b1 + l * 256,
            W2t + (size_t)l * 65536, b2 + l * 256, y2,
            colsum + l * 256, colsumsq + l * 256);
        bn_res_kernel<<<nb8, 256, 0, stream>>>(
            y2, colsum + l * 256, colsumsq + l * 256, gamma + l * 256, beta + l * 256,
            h, (l == 4) ? (float*)d_out : h, h_bf, (l < 4) ? 1 : 0, invN, NN * 32);
    }
}

// Round 17
// 575.804 us; speedup vs baseline: 1.0576x; 1.0576x over previous
//
#include <hip/hip_runtime.h>

typedef unsigned short u16;
typedef __attribute__((ext_vector_type(4))) float f32x4;
typedef __attribute__((ext_vector_type(8))) short s16x8;   // MFMA bf16 frag (8 bf16)
typedef __attribute__((ext_vector_type(8))) unsigned short u16x8;
typedef __attribute__((ext_vector_type(4))) unsigned short u16x4;
typedef __attribute__((ext_vector_type(2))) unsigned u32x2;

__device__ inline float bf2f(u16 u) {
    unsigned v = ((unsigned)u) << 16;
    return __builtin_bit_cast(float, v);
}
__device__ inline u16 f2bf(float f) {
    unsigned u = __builtin_bit_cast(unsigned, f);
    unsigned r = (u + 0x7FFFu + ((u >> 16) & 1u)) >> 16;
    return (u16)r;
}
// truncating pack of two f32 -> two bf16 in one u32 (lo = first). ~2 VALU ops (v_perm-able).
__device__ inline unsigned pk_trunc(float lo, float hi) {
    unsigned a = __builtin_bit_cast(unsigned, lo);
    unsigned b = __builtin_bit_cast(unsigned, hi);
    return (a >> 16) | (b & 0xFFFF0000u);
}

// ---------------- CSR build ----------------
__global__ void count_kernel(const int* __restrict__ dst, int E, int* __restrict__ counts) {
    int e = blockIdx.x * 256 + threadIdx.x;
    if (e < E) atomicAdd(&counts[dst[e]], 1);
}

__global__ __launch_bounds__(1024) void scan_kernel(const int* __restrict__ counts,
    int* __restrict__ row_start, int* __restrict__ cursor, int NN) {
    __shared__ int sh[1024];
    const int tid = threadIdx.x;
    const int CH = (NN + 1023) / 1024;
    const int base = tid * CH;
    int sum = 0;
    for (int i = 0; i < CH; ++i) { int idx = base + i; if (idx < NN) sum += counts[idx]; }
    sh[tid] = sum; __syncthreads();
    for (int off = 1; off < 1024; off <<= 1) {
        int v = (tid >= off) ? sh[tid - off] : 0;
        __syncthreads();
        sh[tid] += v;
        __syncthreads();
    }
    int run = sh[tid] - sum;  // exclusive prefix
    for (int i = 0; i < CH; ++i) {
        int idx = base + i;
        if (idx <= NN) {
            row_start[idx] = run;
            if (idx < NN) { cursor[idx] = run; run += counts[idx]; }
        }
    }
}

__global__ void pos_kernel(const int* __restrict__ src, const int* __restrict__ dst, int E,
    int* __restrict__ cursor, int* __restrict__ pos, int* __restrict__ src_perm) {
    int e = blockIdx.x * 256 + threadIdx.x;
    if (e < E) {
        int p = atomicAdd(&cursor[dst[e]], 1);
        pos[e] = p;
        src_perm[p] = src[e];
    }
}

// ---------------- degree sort (descending), two-level: LDS hist -> few global atomics ----------------
__global__ __launch_bounds__(256) void deg_hist_kernel(const int* __restrict__ counts, int NN,
                                                       int* __restrict__ hist) {
    __shared__ int lh[1024];
    const int t = threadIdx.x;
    for (int i = t; i < 1024; i += 256) lh[i] = 0;
    __syncthreads();
    int n = blockIdx.x * 256 + t;
    if (n < NN) {
        int d = counts[n];
        int b = (d > 1023) ? 0 : (1023 - d);   // descending degree order
        atomicAdd(&lh[b], 1);
    }
    __syncthreads();
    for (int i = t; i < 1024; i += 256) {
        int c = lh[i];
        if (c) atomicAdd(&hist[i], c);
    }
}

__global__ __launch_bounds__(1024) void scan_hist_kernel(const int* __restrict__ hist,
                                                         int* __restrict__ hcur) {
    __shared__ int sh[1024];
    const int t = threadIdx.x;
    const int own = hist[t];
    sh[t] = own; __syncthreads();
    for (int off = 1; off < 1024; off <<= 1) {
        int v = (t >= off) ? sh[t - off] : 0;
        __syncthreads();
        sh[t] += v;
        __syncthreads();
    }
    hcur[t] = sh[t] - own;   // exclusive prefix
}

__global__ __launch_bounds__(256) void sort_fill_kernel(const int* __restrict__ counts, int NN,
                                 int* __restrict__ hcur, int* __restrict__ sorted) {
    __shared__ int lh[1024];     // local counts -> local rank source
    __shared__ int lbase[1024];  // block's global base per bin
    const int t = threadIdx.x;
    for (int i = t; i < 1024; i += 256) lh[i] = 0;
    __syncthreads();
    int n = blockIdx.x * 256 + t;
    int b = 0, lr = 0;
    const bool valid = n < NN;
    if (valid) {
        int d = counts[n];
        b = (d > 1023) ? 0 : (1023 - d);
        lr = atomicAdd(&lh[b], 1);         // local rank within block+bin (LDS, fast)
    }
    __syncthreads();
    for (int i = t; i < 1024; i += 256) {
        int c = lh[i];
        lbase[i] = c ? atomicAdd(&hcur[i], c) : 0;   // one global atomic per non-empty bin
    }
    __syncthreads();
    if (valid) sorted[lbase[b] + lr] = n;
}

// ---------------- fused setup: permute_pad_eattr + prep(x,Wa,Wet) + W1/W2 transpose ----------------
// Wet layout: [256 cols][32 k]; k<16 = We[k][col], k==16 = be[col], k>16 = 0
// eap layout: [E][32] bf16, dst-sorted, with bf16(1.0) marker at k=16
__global__ __launch_bounds__(256) void setup_fused_kernel(
    const float* __restrict__ ea, const int* __restrict__ pos, int E, int eb,
    const float* __restrict__ x, const float* __restrict__ Wa,
    const float* __restrict__ We, const float* __restrict__ be, int NN, int prepb,
    const float* __restrict__ W1, const float* __restrict__ W2,
    u16* __restrict__ eap_out, u16* __restrict__ x_bf, u16* __restrict__ Wat,
    u16* __restrict__ Wet, u16* __restrict__ W1t, u16* __restrict__ W2t) {
    __shared__ float T[32][33];
    const int b = blockIdx.x;
    if (b < eb) {
        // --- permute edge_attr into dst-sorted order, bf16, padded K 16->32 ---
        int e = b * 256 + threadIdx.x;
        if (e >= E) return;
        const float* r = ea + (size_t)e * 16;
        f32x4 q0 = *(const f32x4*)(r + 0);
        f32x4 q1 = *(const f32x4*)(r + 4);
        f32x4 q2 = *(const f32x4*)(r + 8);
        f32x4 q3 = *(const f32x4*)(r + 12);
        u16x8 v0, v1, m, z;
#pragma unroll
        for (int j = 0; j < 4; ++j) {
            v0[j] = f2bf(q0[j]); v0[4 + j] = f2bf(q1[j]);
            v1[j] = f2bf(q2[j]); v1[4 + j] = f2bf(q3[j]);
            m[j] = 0; m[4 + j] = 0; z[j] = 0; z[4 + j] = 0;
        }
        m[0] = 0x3F80;  // bf16(1.0) -> multiplies the be row of Wet
        u16* o = eap_out + (size_t)pos[e] * 32;
        *(u16x8*)(o + 0) = v0;
        *(u16x8*)(o + 8) = v1;
        *(u16x8*)(o + 16) = m;
        *(u16x8*)(o + 24) = z;
        return;
    }
    if (b < eb + prepb) {
        // --- x -> bf16; Wa -> Wat [256n][64k]; We/be -> Wet [256n][32k] ---
        int i = (b - eb) * 256 + threadIdx.x;
        const int S0 = NN * 16;  // x as vec4
        if (i < S0) {
            f32x4 v = *(const f32x4*)(x + (size_t)i * 4);
            u16x4 o; o.x = f2bf(v[0]); o.y = f2bf(v[1]); o.z = f2bf(v[2]); o.w = f2bf(v[3]);
            *(u16x4*)(x_bf + (size_t)i * 4) = o;
            return;
        }
        i -= S0;
        if (i < 16384) { int n = i >> 6, k = i & 63; Wat[i] = f2bf(Wa[k * 256 + n]); return; }
        i -= 16384;
        if (i < 8192) {
            int n = i >> 5, k = i & 31;
            float v = (k < 16) ? We[k * 256 + n] : ((k == 16) ? be[n] : 0.f);
            Wet[i] = f2bf(v);
        }
        return;
    }
    // --- LDS-tiled transpose of W1/W2: Wt[l][n][k] = W[l][k][n] ---
    const int bb = b - eb - prepb;            // 0..639
    const int m5 = bb >> 6;                   // 0..9
    const int rem = bb & 63;
    const int k0 = (rem & 7) * 32, n0 = (rem >> 3) * 32;
    const float* srcw = (m5 < 5) ? (W1 + (size_t)m5 * 65536) : (W2 + (size_t)(m5 - 5) * 65536);
    u16* dstw = (m5 < 5) ? (W1t + (size_t)m5 * 65536) : (W2t + (size_t)(m5 - 5) * 65536);
    const int tx = threadIdx.x & 31, ty = threadIdx.x >> 5;  // 32 x 8
#pragma unroll
    for (int i = 0; i < 4; ++i)
        T[ty + 8 * i][tx] = srcw[(size_t)(k0 + ty + 8 * i) * 256 + n0 + tx];
    __syncthreads();
#pragma unroll
    for (int i = 0; i < 4; ++i)
        dstw[(size_t)(n0 + ty + 8 * i) * 256 + k0 + tx] = f2bf(T[tx][ty + 8 * i]);
}

// ---------------- MFMA GEMM (f32 + bf16 out, used for h0) ----------------
__global__ __launch_bounds__(256) void gemm_h0_kernel(
    const u16* __restrict__ A, int lda, int M,
    const u16* __restrict__ Bt, int K,
    const float* __restrict__ bias,
    float* __restrict__ outF, u16* __restrict__ outB, int ldo) {
    __shared__ u16 As[128 * 32];
    __shared__ u16 Bs[128 * 32];
    const int tid = threadIdx.x, lane = tid & 63, wave = tid >> 6;
    const int m0 = blockIdx.x * 128, n0 = blockIdx.y * 128;
    const int wr = (wave >> 1) * 64, wc = (wave & 1) * 64;

    const f32x4 zero4 = {0.f, 0.f, 0.f, 0.f};
    f32x4 acc[4][4];
#pragma unroll
    for (int m = 0; m < 4; ++m)
#pragma unroll
        for (int n = 0; n < 4; ++n) acc[m][n] = zero4;

    for (int k0 = 0; k0 < K; k0 += 32) {
#pragma unroll
        for (int i = 0; i < 2; ++i) {
            int seg = i * 256 + tid;
            int row = seg >> 2, sk = seg & 3;
            int gr = m0 + row; gr = gr < M ? gr : M - 1;
            u16x8 va = *(const u16x8*)(A + (size_t)gr * lda + k0 + sk * 8);
            *(u16x8*)(&As[row * 32 + sk * 8]) = va;
            u16x8 vb = *(const u16x8*)(Bt + (size_t)(n0 + row) * K + k0 + sk * 8);
            *(u16x8*)(&Bs[row * 32 + sk * 8]) = vb;
        }
        __syncthreads();
        const int rsel = lane & 15, koff = (lane >> 4) * 8;
        s16x8 af[4], bf[4];
#pragma unroll
        for (int m = 0; m < 4; ++m) af[m] = *(const s16x8*)(&As[(wr + m * 16 + rsel) * 32 + koff]);
#pragma unroll
        for (int n = 0; n < 4; ++n) bf[n] = *(const s16x8*)(&Bs[(wc + n * 16 + rsel) * 32 + koff]);
#pragma unroll
        for (int m = 0; m < 4; ++m)
#pragma unroll
            for (int n = 0; n < 4; ++n)
                acc[m][n] = __builtin_amdgcn_mfma_f32_16x16x32_bf16(af[m], bf[n], acc[m][n], 0, 0, 0);
        __syncthreads();
    }

    const int cl = lane & 15, rq = lane >> 4;
#pragma unroll
    for (int n = 0; n < 4; ++n) {
        const int gcol = n0 + wc + n * 16 + cl;
        const float bv = bias[gcol];
#pragma unroll
        for (int m = 0; m < 4; ++m) {
#pragma unroll
            for (int j = 0; j < 4; ++j) {
                int grow = m0 + wr + m * 16 + rq * 4 + j;
                if (grow < M) {
                    float v = acc[m][n][j] + bv;
                    outF[(size_t)grow * ldo + gcol] = v;
                    outB[(size_t)grow * ldo + gcol] = f2bf(v);
                }
            }
        }
    }
}

// ---------------- fused MLP: y2 = relu(z@W1+b1)@W2+b2, with BN col stats ----------------
__global__ __launch_bounds__(256) void mlp_fused_kernel(
    const u16* __restrict__ z, int M,
    const u16* __restrict__ W1t, const float* __restrict__ b1,
    const u16* __restrict__ W2t, const float* __restrict__ b2,
    u16* __restrict__ y2,
    float* __restrict__ colsum, float* __restrict__ colsumsq) {
    __shared__ u16 As[64 * 32];     // 4 KB
    __shared__ u16 Bs[256 * 32];    // 16 KB
    __shared__ u16 Ys[64 * 260];    // 33.3 KB
    const int tid = threadIdx.x, lane = tid & 63, wave = tid >> 6;
    const int m0 = blockIdx.x * 64;
    const int wc = wave * 64;
    const int rsel = lane & 15, koff = (lane >> 4) * 8;
    const int cl = lane & 15, rq = lane >> 4;

    const f32x4 zero4 = {0.f, 0.f, 0.f, 0.f};
    f32x4 acc[4][4];
#pragma unroll
    for (int m = 0; m < 4; ++m)
#pragma unroll
        for (int n = 0; n < 4; ++n) acc[m][n] = zero4;

    // ---- phase 1: y1 = z @ W1 ----
    for (int k0 = 0; k0 < 256; k0 += 32) {
        {
            int row = tid >> 2, sk = tid & 3;
            int gr = m0 + row; gr = gr < M ? gr : M - 1;
            u16x8 va = *(const u16x8*)(z + (size_t)gr * 256 + k0 + sk * 8);
            *(u16x8*)(&As[row * 32 + sk * 8]) = va;
        }
#pragma unroll
        for (int i = 0; i < 4; ++i) {
            int seg = i * 256 + tid;
            int row = seg >> 2, sk = seg & 3;
            u16x8 vb = *(const u16x8*)(W1t + (size_t)row * 256 + k0 + sk * 8);
            *(u16x8*)(&Bs[row * 32 + sk * 8]) = vb;
        }
        __syncthreads();
        s16x8 af[4], bf[4];
#pragma unroll
        for (int m = 0; m < 4; ++m) af[m] = *(const s16x8*)(&As[(m * 16 + rsel) * 32 + koff]);
#pragma unroll
        for (int n = 0; n < 4; ++n) bf[n] = *(const s16x8*)(&Bs[(wc + n * 16 + rsel) * 32 + koff]);
#pragma unroll
        for (int m = 0; m < 4; ++m)
#pragma unroll
            for (int n = 0; n < 4; ++n)
                acc[m][n] = __builtin_amdgcn_mfma_f32_16x16x32_bf16(af[m], bf[n], acc[m][n], 0, 0, 0);
        __syncthreads();
    }
    // epilogue 1: relu(y1 + b1) -> Ys
#pragma unroll
    for (int n = 0; n < 4; ++n) {
        const int gcol = wc + n * 16 + cl;
        const float bv = b1[gcol];
#pragma unroll
        for (int m = 0; m < 4; ++m) {
#pragma unroll
            for (int j = 0; j < 4; ++j) {
                int row = m * 16 + rq * 4 + j;
                float v = fmaxf(acc[m][n][j] + bv, 0.f);
                Ys[row * 260 + gcol] = f2bf(v);
            }
        }
        acc[0][n] = zero4; acc[1][n] = zero4; acc[2][n] = zero4; acc[3][n] = zero4;
    }

    // ---- phase 2: y2 = relu_y1 @ W2 ----
    for (int k0 = 0; k0 < 256; k0 += 32) {
#pragma unroll
        for (int i = 0; i < 4; ++i) {
            int seg = i * 256 + tid;
            int row = seg >> 2, sk = seg & 3;
            u16x8 vb = *(const u16x8*)(W2t + (size_t)row * 256 + k0 + sk * 8);
            *(u16x8*)(&Bs[row * 32 + sk * 8]) = vb;
        }
        __syncthreads();
        s16x8 af[4], bf[4];
#pragma unroll
        for (int m = 0; m < 4; ++m) af[m] = *(const s16x8*)(&Ys[(m * 16 + rsel) * 260 + k0 + koff]);
#pragma unroll
        for (int n = 0; n < 4; ++n) bf[n] = *(const s16x8*)(&Bs[(wc + n * 16 + rsel) * 32 + koff]);
#pragma unroll
        for (int m = 0; m < 4; ++m)
#pragma unroll
            for (int n = 0; n < 4; ++n)
                acc[m][n] = __builtin_amdgcn_mfma_f32_16x16x32_bf16(af[m], bf[n], acc[m][n], 0, 0, 0);
        __syncthreads();
    }
    // epilogue 2: stats + stage into Ys, then coalesced write
#pragma unroll
    for (int n = 0; n < 4; ++n) {
        const int gcol = wc + n * 16 + cl;
        const float bv = b2[gcol];
        float s = 0.f, ss = 0.f;
#pragma unroll
        for (int m = 0; m < 4; ++m) {
#pragma unroll
            for (int j = 0; j < 4; ++j) {
                int row = m * 16 + rq * 4 + j;
                float v = acc[m][n][j] + bv;
                Ys[row * 260 + gcol] = f2bf(v);
                if (m0 + row < M) { s += v; ss += v * v; }
            }
        }
        s += __shfl_down(s, 32); ss += __shfl_down(ss, 32);
        s += __shfl_down(s, 16); ss += __shfl_down(ss, 16);
        if (rq == 0) {
            atomicAdd(&colsum[gcol], s);
            atomicAdd(&colsumsq[gcol], ss);
        }
    }
    __syncthreads();
    for (int r0 = 0; r0 < 64; r0 += 8) {
        int row = r0 + (tid >> 5);
        int gr = m0 + row;
        int cc = (tid & 31) * 8;
        if (gr < M) *(u16x8*)(y2 + (size_t)gr * 256 + cc) = *(u16x8*)(&Ys[row * 260 + cc]);
    }
}

// ---------------- aggregation: MFMA edge-projection into wave-private LDS tile,
// then coalesced accumulate. Degree-sorted node order, 4-wave blocks.
// ET store uses truncating bf16 pack (1-2 VALU per pair vs 8 for RNE).
// No __syncthreads (wave-local LDS). ----------------
__global__ __launch_bounds__(256) void agg_rc_kernel(
    const int* __restrict__ sorted_nodes,
    const int* __restrict__ row_start, const int* __restrict__ src_perm,
    const u16* __restrict__ eap, const u16* __restrict__ Wet,
    const u16* __restrict__ h_bf,
    const float* __restrict__ eps, int layer,
    u16* __restrict__ z_bf, int NN) {
    __shared__ u16 ET[4 * 16 * 264];   // 4 waves x (16 edges x 264-stride bf16)
    const int tid = threadIdx.x;
    const int lane = tid & 63;
    const int wv = tid >> 6;
    const int rsel = lane & 15;
    const int q = lane >> 4;
    const int half = lane >> 5;
    const int c0 = (lane & 31) * 8;
    u16* et = &ET[wv * 16 * 264];

    // Wet A-fragments in registers: lane holds Wet[b*16+rsel][q*8..+7] for each col-block b
    s16x8 wf[16];
#pragma unroll
    for (int b = 0; b < 16; ++b)
        wf[b] = *(const s16x8*)(Wet + (b * 16 + rsel) * 32 + q * 8);

    const int idx = blockIdx.x * 4 + wv;
    if (idx >= NN) return;
    const int node = sorted_nodes[idx];
    const int s0 = row_start[node], s1 = row_start[node + 1];

    const f32x4 zero4 = {0.f, 0.f, 0.f, 0.f};
    float a[8] = {0.f, 0.f, 0.f, 0.f, 0.f, 0.f, 0.f, 0.f};

    for (int e0 = s0; e0 < s1; e0 += 16) {
        // --- project 16 edges: e = ea @ We + be, D[col][edge] -> LDS tile ---
        const int ec = (e0 + rsel < s1) ? (e0 + rsel) : (s1 - 1);
        s16x8 eaf = *(const s16x8*)(eap + (size_t)ec * 32 + q * 8);
#pragma unroll
        for (int b = 0; b < 16; ++b) {
            f32x4 d = __builtin_amdgcn_mfma_f32_16x16x32_bf16(wf[b], eaf, zero4, 0, 0, 0);
            u32x2 w;
            w[0] = pk_trunc(d[0], d[1]);
            w[1] = pk_trunc(d[2], d[3]);
            *(u32x2*)(et + rsel * 264 + b * 16 + q * 4) = w;   // lane owns edge=rsel, cols b*16+q*4..+3
        }
        // --- accumulate: half-wave per edge, 16B loads, 4 edges in flight ---
        const int cnt = (s1 - e0 < 16) ? (s1 - e0) : 16;
        for (int kk = 0; kk < cnt; kk += 4) {
            const int ka = kk + half, kb = kk + 2 + half;
            const bool v0 = ka < cnt, v1 = kb < cnt;
            const int ia = v0 ? (e0 + ka) : (s1 - 1);
            const int ib = v1 ? (e0 + kb) : (s1 - 1);
            const int sa = src_perm[ia];
            const int sb = src_perm[ib];
            u16x8 h0 = *(const u16x8*)(h_bf + (size_t)sa * 256 + c0);
            u16x8 h1 = *(const u16x8*)(h_bf + (size_t)sb * 256 + c0);
            u16x8 e8a = *(const u16x8*)(et + (v0 ? ka : 0) * 264 + c0);
            u16x8 e8b = *(const u16x8*)(et + (v1 ? kb : 0) * 264 + c0);
            const float m0 = v0 ? 1.f : 0.f;
            const float m1 = v1 ? 1.f : 0.f;
#pragma unroll
            for (int j = 0; j < 8; ++j) {
                a[j] += m0 * fmaxf(bf2f((u16)e8a[j]) + bf2f((u16)h0[j]), 0.f);
                a[j] += m1 * fmaxf(bf2f((u16)e8b[j]) + bf2f((u16)h1[j]), 0.f);
            }
        }
    }
#pragma unroll
    for (int j = 0; j < 8; ++j) a[j] += __shfl_xor(a[j], 32);
    if (half == 0) {
        const float c = 1.f + eps[layer];
        u16x8 hbv = *(const u16x8*)(h_bf + (size_t)node * 256 + c0);
        u16x8 z;
#pragma unroll
        for (int j = 0; j < 8; ++j)
            z[j] = f2bf(c * bf2f((u16)hbv[j]) + a[j]);
        *(u16x8*)(z_bf + (size_t)node * 256 + c0) = z;
    }
}

// ---------------- BN + relu + residual (8 elements/thread) ----------------
__global__ __launch_bounds__(256) void bn_res_kernel(
    const u16* __restrict__ y2, const float* __restrict__ colsum,
    const float* __restrict__ colsumsq, const float* __restrict__ gamma,
    const float* __restrict__ beta, const float* __restrict__ hin,
    float* __restrict__ hout, u16* __restrict__ h_bf, int write_bf,
    float invN, int total8) {
    const int i = blockIdx.x * 256 + threadIdx.x;
    if (i >= total8) return;
    const size_t base = (size_t)i * 8;
    const int c0 = (int)(base & 255);
    u16x8 yv = *(const u16x8*)(y2 + base);
    f32x4 hv0 = *(const f32x4*)(hin + base);
    f32x4 hv1 = *(const f32x4*)(hin + base + 4);
    float res[8];
#pragma unroll
    for (int j = 0; j < 8; ++j) {
        const int c = c0 + j;
        const float mu = colsum[c] * invN;
        const float var = colsumsq[c] * invN - mu * mu;
        const float sc = gamma[c] * rsqrtf(var + 1e-5f);
        const float sh = beta[c] - mu * sc;
        float v = bf2f((u16)yv[j]) * sc + sh;
        v = fmaxf(v, 0.f);
        res[j] = ((j < 4) ? hv0[j] : hv1[j - 4]) + v;
    }
    f32x4 o0, o1;
#pragma unroll
    for (int j = 0; j < 4; ++j) { o0[j] = res[j]; o1[j] = res[4 + j]; }
    *(f32x4*)(hout + base) = o0;
    *(f32x4*)(hout + base + 4) = o1;
    if (write_bf) {
        u16x8 hb;
#pragma unroll
        for (int j = 0; j < 8; ++j) hb[j] = f2bf(res[j]);
        *(u16x8*)(h_bf + base) = hb;
    }
}

extern "C" void kernel_launch(void* const* d_in, const int* in_sizes, int n_in,
                              void* d_out, int out_size, void* d_ws, size_t ws_size,
                              hipStream_t stream) {
    const float* x    = (const float*)d_in[0];
    const float* ea   = (const float*)d_in[1];
    const int*   ei   = (const int*)d_in[2];
    const float* Wa   = (const float*)d_in[3];
    const float* ba   = (const float*)d_in[4];
    const float* We   = (const float*)d_in[5];
    const float* be   = (const float*)d_in[6];
    const float* eps  = (const float*)d_in[7];
    const float* W1   = (const float*)d_in[8];
    const float* b1   = (const float*)d_in[9];
    const float* W2   = (const float*)d_in[10];
    const float* b2   = (const float*)d_in[11];
    const float* gamma= (const float*)d_in[12];
    const float* beta = (const float*)d_in[13];

    const int NN = in_sizes[0] / 64;
    const int EE = in_sizes[1] / 16;
    const int* src = ei;
    const int* dst = ei + EE;

    char* p = (char*)d_ws;
    auto alloc = [&](size_t bytes) -> char* {
        char* r = p;
        p += (bytes + 255) & ~(size_t)255;
        return r;
    };
    int*   counts   = (int*)alloc((size_t)(NN + 1) * 4);   // zeroed region start
    float* colsum   = (float*)alloc(5 * 256 * 4);
    float* colsumsq = (float*)alloc(5 * 256 * 4);
    int*   hist     = (int*)alloc(1024 * 4);
    size_t zbytes   = (size_t)(p - (char*)counts);
    int*   hcur     = (int*)alloc(1024 * 4);
    int*   sorted   = (int*)alloc((size_t)NN * 4);
    int*   row_start= (int*)alloc((size_t)(NN + 1) * 4);
    int*   cursor   = (int*)alloc((size_t)NN * 4);
    int*   pos      = (int*)alloc((size_t)EE * 4);
    int*   src_perm = (int*)alloc((size_t)EE * 4);
    u16*   x_bf     = (u16*)alloc((size_t)NN * 64 * 2);
    u16*   Wat      = (u16*)alloc(256 * 64 * 2);
    u16*   Wet      = (u16*)alloc(256 * 32 * 2);
    u16*   W1t      = (u16*)alloc((size_t)5 * 65536 * 2);
    u16*   W2t      = (u16*)alloc((size_t)5 * 65536 * 2);
    u16*   eap_perm = (u16*)alloc((size_t)EE * 32 * 2);
    float* h        = (float*)alloc((size_t)NN * 256 * 4);
    u16*   h_bf     = (u16*)alloc((size_t)NN * 256 * 2);
    u16*   z_bf     = (u16*)alloc((size_t)NN * 256 * 2);
    u16*   y2       = (u16*)alloc((size_t)NN * 256 * 2);

    hipMemsetAsync(counts, 0, zbytes, stream);

    const int eb = (EE + 255) / 256;
    const int nb = (NN + 255) / 256;
    count_kernel<<<eb, 256, 0, stream>>>(dst, EE, counts);
    scan_kernel<<<1, 1024, 0, stream>>>(counts, row_start, cursor, NN);
    pos_kernel<<<eb, 256, 0, stream>>>(src, dst, EE, cursor, pos, src_perm);

    // degree sort (descending) for agg block balance -- two-level, low-contention
    deg_hist_kernel<<<nb, 256, 0, stream>>>(counts, NN, hist);
    scan_hist_kernel<<<1, 1024, 0, stream>>>(hist, hcur);
    sort_fill_kernel<<<nb, 256, 0, stream>>>(counts, NN, hcur, sorted);

    const int prep_total = NN * 16 + 16384 + 8192;
    const int prepb = (prep_total + 255) / 256;
    const int setup_blocks = eb + prepb + 640;
    setup_fused_kernel<<<setup_blocks, 256, 0, stream>>>(
        ea, pos, EE, eb, x, Wa, We, be, NN, prepb, W1, W2,
        eap_perm, x_bf, Wat, Wet, W1t, W2t);

    // h0 = x @ Wa + ba  -> h (f32) and h_bf (bf16)
    dim3 gh((NN + 127) / 128, 2);
    gemm_h0_kernel<<<gh, 256, 0, stream>>>(
        x_bf, 64, NN, Wat, 64, ba, h, h_bf, 256);

    const float invN = 1.f / (float)NN;
    const int nb8 = (NN * 32 + 255) / 256;
    const int mlp_blocks = (NN + 63) / 64;
    for (int l = 0; l < 5; ++l) {
        agg_rc_kernel<<<(NN + 3) / 4, 256, 0, stream>>>(
            sorted, row_start, src_perm, eap_perm, Wet, h_bf, eps, l, z_bf, NN);
        mlp_fused_kernel<<<mlp_blocks, 256, 0, stream>>>(
            z_bf, NN, W1t + (size_t)l * 65536, b1 + l * 256,
            W2t + (size_t)l * 65536, b2 + l * 256, y2,
            colsum + l * 256, colsumsq + l * 256);
        bn_res_kernel<<<nb8, 256, 0, stream>>>(
            y2, colsum + l * 256, colsumsq + l * 256, gamma + l * 256, beta + l * 256,
            h, (l == 4) ? (float*)d_out : h, h_bf, (l < 4) ? 1 : 0, invN, NN * 32);
    }
}

// Round 18
// 575.670 us; speedup vs baseline: 1.0578x; 1.0002x over previous
//
#include <hip/hip_runtime.h>

typedef unsigned short u16;
typedef __attribute__((ext_vector_type(4))) float f32x4;
typedef __attribute__((ext_vector_type(8))) short s16x8;   // MFMA bf16 frag (8 bf16)
typedef __attribute__((ext_vector_type(8))) unsigned short u16x8;
typedef __attribute__((ext_vector_type(4))) unsigned short u16x4;
typedef __attribute__((ext_vector_type(2))) unsigned u32x2;

__device__ inline float bf2f(u16 u) {
    unsigned v = ((unsigned)u) << 16;
    return __builtin_bit_cast(float, v);
}
__device__ inline u16 f2bf(float f) {
    unsigned u = __builtin_bit_cast(unsigned, f);
    unsigned r = (u + 0x7FFFu + ((u >> 16) & 1u)) >> 16;
    return (u16)r;
}
// truncating pack of two f32 -> two bf16 in one u32 (lo = first). ~2 VALU ops (v_perm-able).
__device__ inline unsigned pk_trunc(float lo, float hi) {
    unsigned a = __builtin_bit_cast(unsigned, lo);
    unsigned b = __builtin_bit_cast(unsigned, hi);
    return (a >> 16) | (b & 0xFFFF0000u);
}

// ---------------- CSR build ----------------
__global__ void count_kernel(const int* __restrict__ dst, int E, int* __restrict__ counts) {
    int e = blockIdx.x * 256 + threadIdx.x;
    if (e < E) atomicAdd(&counts[dst[e]], 1);
}

__global__ __launch_bounds__(1024) void scan_kernel(const int* __restrict__ counts,
    int* __restrict__ row_start, int* __restrict__ cursor, int NN) {
    __shared__ int sh[1024];
    const int tid = threadIdx.x;
    const int CH = (NN + 1023) / 1024;
    const int base = tid * CH;
    int sum = 0;
    for (int i = 0; i < CH; ++i) { int idx = base + i; if (idx < NN) sum += counts[idx]; }
    sh[tid] = sum; __syncthreads();
    for (int off = 1; off < 1024; off <<= 1) {
        int v = (tid >= off) ? sh[tid - off] : 0;
        __syncthreads();
        sh[tid] += v;
        __syncthreads();
    }
    int run = sh[tid] - sum;  // exclusive prefix
    for (int i = 0; i < CH; ++i) {
        int idx = base + i;
        if (idx <= NN) {
            row_start[idx] = run;
            if (idx < NN) { cursor[idx] = run; run += counts[idx]; }
        }
    }
}

__global__ void pos_kernel(const int* __restrict__ src, const int* __restrict__ dst, int E,
    int* __restrict__ cursor, int* __restrict__ pos, int* __restrict__ src_perm) {
    int e = blockIdx.x * 256 + threadIdx.x;
    if (e < E) {
        int p = atomicAdd(&cursor[dst[e]], 1);
        pos[e] = p;
        src_perm[p] = src[e];
    }
}

// ---------------- degree sort (descending), two-level: LDS hist -> few global atomics ----------------
__global__ __launch_bounds__(256) void deg_hist_kernel(const int* __restrict__ counts, int NN,
                                                       int* __restrict__ hist) {
    __shared__ int lh[1024];
    const int t = threadIdx.x;
    for (int i = t; i < 1024; i += 256) lh[i] = 0;
    __syncthreads();
    int n = blockIdx.x * 256 + t;
    if (n < NN) {
        int d = counts[n];
        int b = (d > 1023) ? 0 : (1023 - d);   // descending degree order
        atomicAdd(&lh[b], 1);
    }
    __syncthreads();
    for (int i = t; i < 1024; i += 256) {
        int c = lh[i];
        if (c) atomicAdd(&hist[i], c);
    }
}

__global__ __launch_bounds__(1024) void scan_hist_kernel(const int* __restrict__ hist,
                                                         int* __restrict__ hcur) {
    __shared__ int sh[1024];
    const int t = threadIdx.x;
    const int own = hist[t];
    sh[t] = own; __syncthreads();
    for (int off = 1; off < 1024; off <<= 1) {
        int v = (t >= off) ? sh[t - off] : 0;
        __syncthreads();
        sh[t] += v;
        __syncthreads();
    }
    hcur[t] = sh[t] - own;   // exclusive prefix
}

__global__ __launch_bounds__(256) void sort_fill_kernel(const int* __restrict__ counts, int NN,
                                 int* __restrict__ hcur, int* __restrict__ sorted) {
    __shared__ int lh[1024];     // local counts -> local rank source
    __shared__ int lbase[1024];  // block's global base per bin
    const int t = threadIdx.x;
    for (int i = t; i < 1024; i += 256) lh[i] = 0;
    __syncthreads();
    int n = blockIdx.x * 256 + t;
    int b = 0, lr = 0;
    const bool valid = n < NN;
    if (valid) {
        int d = counts[n];
        b = (d > 1023) ? 0 : (1023 - d);
        lr = atomicAdd(&lh[b], 1);         // local rank within block+bin (LDS, fast)
    }
    __syncthreads();
    for (int i = t; i < 1024; i += 256) {
        int c = lh[i];
        lbase[i] = c ? atomicAdd(&hcur[i], c) : 0;   // one global atomic per non-empty bin
    }
    __syncthreads();
    if (valid) sorted[lbase[b] + lr] = n;
}

// ---------------- fused setup: permute_pad_eattr + prep(x,Wa,Wet) + W1/W2 transpose ----------------
// Wet layout: [256 cols][32 k]; k<16 = We[k][col], k==16 = be[col], k>16 = 0
// eap layout: [E][32] bf16, dst-sorted, with bf16(1.0) marker at k=16
__global__ __launch_bounds__(256) void setup_fused_kernel(
    const float* __restrict__ ea, const int* __restrict__ pos, int E, int eb,
    const float* __restrict__ x, const float* __restrict__ Wa,
    const float* __restrict__ We, const float* __restrict__ be, int NN, int prepb,
    const float* __restrict__ W1, const float* __restrict__ W2,
    u16* __restrict__ eap_out, u16* __restrict__ x_bf, u16* __restrict__ Wat,
    u16* __restrict__ Wet, u16* __restrict__ W1t, u16* __restrict__ W2t) {
    __shared__ float T[32][33];
    const int b = blockIdx.x;
    if (b < eb) {
        // --- permute edge_attr into dst-sorted order, bf16, padded K 16->32 ---
        int e = b * 256 + threadIdx.x;
        if (e >= E) return;
        const float* r = ea + (size_t)e * 16;
        f32x4 q0 = *(const f32x4*)(r + 0);
        f32x4 q1 = *(const f32x4*)(r + 4);
        f32x4 q2 = *(const f32x4*)(r + 8);
        f32x4 q3 = *(const f32x4*)(r + 12);
        u16x8 v0, v1, m, z;
#pragma unroll
        for (int j = 0; j < 4; ++j) {
            v0[j] = f2bf(q0[j]); v0[4 + j] = f2bf(q1[j]);
            v1[j] = f2bf(q2[j]); v1[4 + j] = f2bf(q3[j]);
            m[j] = 0; m[4 + j] = 0; z[j] = 0; z[4 + j] = 0;
        }
        m[0] = 0x3F80;  // bf16(1.0) -> multiplies the be row of Wet
        u16* o = eap_out + (size_t)pos[e] * 32;
        *(u16x8*)(o + 0) = v0;
        *(u16x8*)(o + 8) = v1;
        *(u16x8*)(o + 16) = m;
        *(u16x8*)(o + 24) = z;
        return;
    }
    if (b < eb + prepb) {
        // --- x -> bf16; Wa -> Wat [256n][64k]; We/be -> Wet [256n][32k] ---
        int i = (b - eb) * 256 + threadIdx.x;
        const int S0 = NN * 16;  // x as vec4
        if (i < S0) {
            f32x4 v = *(const f32x4*)(x + (size_t)i * 4);
            u16x4 o; o.x = f2bf(v[0]); o.y = f2bf(v[1]); o.z = f2bf(v[2]); o.w = f2bf(v[3]);
            *(u16x4*)(x_bf + (size_t)i * 4) = o;
            return;
        }
        i -= S0;
        if (i < 16384) { int n = i >> 6, k = i & 63; Wat[i] = f2bf(Wa[k * 256 + n]); return; }
        i -= 16384;
        if (i < 8192) {
            int n = i >> 5, k = i & 31;
            float v = (k < 16) ? We[k * 256 + n] : ((k == 16) ? be[n] : 0.f);
            Wet[i] = f2bf(v);
        }
        return;
    }
    // --- LDS-tiled transpose of W1/W2: Wt[l][n][k] = W[l][k][n] ---
    const int bb = b - eb - prepb;            // 0..639
    const int m5 = bb >> 6;                   // 0..9
    const int rem = bb & 63;
    const int k0 = (rem & 7) * 32, n0 = (rem >> 3) * 32;
    const float* srcw = (m5 < 5) ? (W1 + (size_t)m5 * 65536) : (W2 + (size_t)(m5 - 5) * 65536);
    u16* dstw = (m5 < 5) ? (W1t + (size_t)m5 * 65536) : (W2t + (size_t)(m5 - 5) * 65536);
    const int tx = threadIdx.x & 31, ty = threadIdx.x >> 5;  // 32 x 8
#pragma unroll
    for (int i = 0; i < 4; ++i)
        T[ty + 8 * i][tx] = srcw[(size_t)(k0 + ty + 8 * i) * 256 + n0 + tx];
    __syncthreads();
#pragma unroll
    for (int i = 0; i < 4; ++i)
        dstw[(size_t)(n0 + ty + 8 * i) * 256 + k0 + tx] = f2bf(T[tx][ty + 8 * i]);
}

// ---------------- MFMA GEMM (f32 + bf16 out, used for h0) ----------------
__global__ __launch_bounds__(256) void gemm_h0_kernel(
    const u16* __restrict__ A, int lda, int M,
    const u16* __restrict__ Bt, int K,
    const float* __restrict__ bias,
    float* __restrict__ outF, u16* __restrict__ outB, int ldo) {
    __shared__ u16 As[128 * 32];
    __shared__ u16 Bs[128 * 32];
    const int tid = threadIdx.x, lane = tid & 63, wave = tid >> 6;
    const int m0 = blockIdx.x * 128, n0 = blockIdx.y * 128;
    const int wr = (wave >> 1) * 64, wc = (wave & 1) * 64;

    const f32x4 zero4 = {0.f, 0.f, 0.f, 0.f};
    f32x4 acc[4][4];
#pragma unroll
    for (int m = 0; m < 4; ++m)
#pragma unroll
        for (int n = 0; n < 4; ++n) acc[m][n] = zero4;

    for (int k0 = 0; k0 < K; k0 += 32) {
#pragma unroll
        for (int i = 0; i < 2; ++i) {
            int seg = i * 256 + tid;
            int row = seg >> 2, sk = seg & 3;
            int gr = m0 + row; gr = gr < M ? gr : M - 1;
            u16x8 va = *(const u16x8*)(A + (size_t)gr * lda + k0 + sk * 8);
            *(u16x8*)(&As[row * 32 + sk * 8]) = va;
            u16x8 vb = *(const u16x8*)(Bt + (size_t)(n0 + row) * K + k0 + sk * 8);
            *(u16x8*)(&Bs[row * 32 + sk * 8]) = vb;
        }
        __syncthreads();
        const int rsel = lane & 15, koff = (lane >> 4) * 8;
        s16x8 af[4], bf[4];
#pragma unroll
        for (int m = 0; m < 4; ++m) af[m] = *(const s16x8*)(&As[(wr + m * 16 + rsel) * 32 + koff]);
#pragma unroll
        for (int n = 0; n < 4; ++n) bf[n] = *(const s16x8*)(&Bs[(wc + n * 16 + rsel) * 32 + koff]);
#pragma unroll
        for (int m = 0; m < 4; ++m)
#pragma unroll
            for (int n = 0; n < 4; ++n)
                acc[m][n] = __builtin_amdgcn_mfma_f32_16x16x32_bf16(af[m], bf[n], acc[m][n], 0, 0, 0);
        __syncthreads();
    }

    const int cl = lane & 15, rq = lane >> 4;
#pragma unroll
    for (int n = 0; n < 4; ++n) {
        const int gcol = n0 + wc + n * 16 + cl;
        const float bv = bias[gcol];
#pragma unroll
        for (int m = 0; m < 4; ++m) {
#pragma unroll
            for (int j = 0; j < 4; ++j) {
                int grow = m0 + wr + m * 16 + rq * 4 + j;
                if (grow < M) {
                    float v = acc[m][n][j] + bv;
                    outF[(size_t)grow * ldo + gcol] = v;
                    outB[(size_t)grow * ldo + gcol] = f2bf(v);
                }
            }
        }
    }
}

// ---------------- fused MLP (32-row tiles for 2x grid fill): y2 = relu(z@W1+b1)@W2+b2 ----------------
__global__ __launch_bounds__(256) void mlp_fused_kernel(
    const u16* __restrict__ z, int M,
    const u16* __restrict__ W1t, const float* __restrict__ b1,
    const u16* __restrict__ W2t, const float* __restrict__ b2,
    u16* __restrict__ y2,
    float* __restrict__ colsum, float* __restrict__ colsumsq) {
    __shared__ u16 As[32 * 32];     // 2 KB
    __shared__ u16 Bs[256 * 32];    // 16 KB
    __shared__ u16 Ys[32 * 260];    // 16.6 KB
    const int tid = threadIdx.x, lane = tid & 63, wave = tid >> 6;
    const int m0 = blockIdx.x * 32;
    const int wc = wave * 64;
    const int rsel = lane & 15, koff = (lane >> 4) * 8;
    const int cl = lane & 15, rq = lane >> 4;

    const f32x4 zero4 = {0.f, 0.f, 0.f, 0.f};
    f32x4 acc[2][4];
#pragma unroll
    for (int m = 0; m < 2; ++m)
#pragma unroll
        for (int n = 0; n < 4; ++n) acc[m][n] = zero4;

    // ---- phase 1: y1 = z @ W1 ----
    for (int k0 = 0; k0 < 256; k0 += 32) {
        if (tid < 128) {
            int row = tid >> 2, sk = tid & 3;
            int gr = m0 + row; gr = gr < M ? gr : M - 1;
            u16x8 va = *(const u16x8*)(z + (size_t)gr * 256 + k0 + sk * 8);
            *(u16x8*)(&As[row * 32 + sk * 8]) = va;
        }
#pragma unroll
        for (int i = 0; i < 4; ++i) {
            int seg = i * 256 + tid;
            int row = seg >> 2, sk = seg & 3;
            u16x8 vb = *(const u16x8*)(W1t + (size_t)row * 256 + k0 + sk * 8);
            *(u16x8*)(&Bs[row * 32 + sk * 8]) = vb;
        }
        __syncthreads();
        s16x8 af[2], bf[4];
#pragma unroll
        for (int m = 0; m < 2; ++m) af[m] = *(const s16x8*)(&As[(m * 16 + rsel) * 32 + koff]);
#pragma unroll
        for (int n = 0; n < 4; ++n) bf[n] = *(const s16x8*)(&Bs[(wc + n * 16 + rsel) * 32 + koff]);
#pragma unroll
        for (int m = 0; m < 2; ++m)
#pragma unroll
            for (int n = 0; n < 4; ++n)
                acc[m][n] = __builtin_amdgcn_mfma_f32_16x16x32_bf16(af[m], bf[n], acc[m][n], 0, 0, 0);
        __syncthreads();
    }
    // epilogue 1: relu(y1 + b1) -> Ys
#pragma unroll
    for (int n = 0; n < 4; ++n) {
        const int gcol = wc + n * 16 + cl;
        const float bv = b1[gcol];
#pragma unroll
        for (int m = 0; m < 2; ++m) {
#pragma unroll
            for (int j = 0; j < 4; ++j) {
                int row = m * 16 + rq * 4 + j;
                float v = fmaxf(acc[m][n][j] + bv, 0.f);
                Ys[row * 260 + gcol] = f2bf(v);
            }
        }
        acc[0][n] = zero4; acc[1][n] = zero4;
    }

    // ---- phase 2: y2 = relu_y1 @ W2 ----
    for (int k0 = 0; k0 < 256; k0 += 32) {
#pragma unroll
        for (int i = 0; i < 4; ++i) {
            int seg = i * 256 + tid;
            int row = seg >> 2, sk = seg & 3;
            u16x8 vb = *(const u16x8*)(W2t + (size_t)row * 256 + k0 + sk * 8);
            *(u16x8*)(&Bs[row * 32 + sk * 8]) = vb;
        }
        __syncthreads();
        s16x8 af[2], bf[4];
#pragma unroll
        for (int m = 0; m < 2; ++m) af[m] = *(const s16x8*)(&Ys[(m * 16 + rsel) * 260 + k0 + koff]);
#pragma unroll
        for (int n = 0; n < 4; ++n) bf[n] = *(const s16x8*)(&Bs[(wc + n * 16 + rsel) * 32 + koff]);
#pragma unroll
        for (int m = 0; m < 2; ++m)
#pragma unroll
            for (int n = 0; n < 4; ++n)
                acc[m][n] = __builtin_amdgcn_mfma_f32_16x16x32_bf16(af[m], bf[n], acc[m][n], 0, 0, 0);
        __syncthreads();
    }
    // epilogue 2: stats + stage into Ys, then coalesced write
#pragma unroll
    for (int n = 0; n < 4; ++n) {
        const int gcol = wc + n * 16 + cl;
        const float bv = b2[gcol];
        float s = 0.f, ss = 0.f;
#pragma unroll
        for (int m = 0; m < 2; ++m) {
#pragma unroll
            for (int j = 0; j < 4; ++j) {
                int row = m * 16 + rq * 4 + j;
                float v = acc[m][n][j] + bv;
                Ys[row * 260 + gcol] = f2bf(v);
                if (m0 + row < M) { s += v; ss += v * v; }
            }
        }
        s += __shfl_down(s, 32); ss += __shfl_down(ss, 32);
        s += __shfl_down(s, 16); ss += __shfl_down(ss, 16);
        if (rq == 0) {
            atomicAdd(&colsum[gcol], s);
            atomicAdd(&colsumsq[gcol], ss);
        }
    }
    __syncthreads();
    for (int r0 = 0; r0 < 32; r0 += 8) {
        int row = r0 + (tid >> 5);
        int gr = m0 + row;
        int cc = (tid & 31) * 8;
        if (gr < M) *(u16x8*)(y2 + (size_t)gr * 256 + cc) = *(u16x8*)(&Ys[row * 260 + cc]);
    }
}

// ---------------- aggregation: MFMA edge-projection into wave-private LDS tile,
// then coalesced accumulate. Degree-sorted node order, 4-wave blocks.
// ET store uses truncating bf16 pack. No __syncthreads (wave-local LDS). ----------------
__global__ __launch_bounds__(256) void agg_rc_kernel(
    const int* __restrict__ sorted_nodes,
    const int* __restrict__ row_start, const int* __restrict__ src_perm,
    const u16* __restrict__ eap, const u16* __restrict__ Wet,
    const u16* __restrict__ h_bf,
    const float* __restrict__ eps, int layer,
    u16* __restrict__ z_bf, int NN) {
    __shared__ u16 ET[4 * 16 * 264];   // 4 waves x (16 edges x 264-stride bf16)
    const int tid = threadIdx.x;
    const int lane = tid & 63;
    const int wv = tid >> 6;
    const int rsel = lane & 15;
    const int q = lane >> 4;
    const int half = lane >> 5;
    const int c0 = (lane & 31) * 8;
    u16* et = &ET[wv * 16 * 264];

    // Wet A-fragments in registers: lane holds Wet[b*16+rsel][q*8..+7] for each col-block b
    s16x8 wf[16];
#pragma unroll
    for (int b = 0; b < 16; ++b)
        wf[b] = *(const s16x8*)(Wet + (b * 16 + rsel) * 32 + q * 8);

    const int idx = blockIdx.x * 4 + wv;
    if (idx >= NN) return;
    const int node = sorted_nodes[idx];
    const int s0 = row_start[node], s1 = row_start[node + 1];

    const f32x4 zero4 = {0.f, 0.f, 0.f, 0.f};
    float a[8] = {0.f, 0.f, 0.f, 0.f, 0.f, 0.f, 0.f, 0.f};

    for (int e0 = s0; e0 < s1; e0 += 16) {
        // --- project 16 edges: e = ea @ We + be, D[col][edge] -> LDS tile ---
        const int ec = (e0 + rsel < s1) ? (e0 + rsel) : (s1 - 1);
        s16x8 eaf = *(const s16x8*)(eap + (size_t)ec * 32 + q * 8);
#pragma unroll
        for (int b = 0; b < 16; ++b) {
            f32x4 d = __builtin_amdgcn_mfma_f32_16x16x32_bf16(wf[b], eaf, zero4, 0, 0, 0);
            u32x2 w;
            w[0] = pk_trunc(d[0], d[1]);
            w[1] = pk_trunc(d[2], d[3]);
            *(u32x2*)(et + rsel * 264 + b * 16 + q * 4) = w;   // lane owns edge=rsel, cols b*16+q*4..+3
        }
        // --- accumulate: half-wave per edge, 16B loads, 4 edges in flight ---
        const int cnt = (s1 - e0 < 16) ? (s1 - e0) : 16;
        for (int kk = 0; kk < cnt; kk += 4) {
            const int ka = kk + half, kb = kk + 2 + half;
            const bool v0 = ka < cnt, v1 = kb < cnt;
            const int ia = v0 ? (e0 + ka) : (s1 - 1);
            const int ib = v1 ? (e0 + kb) : (s1 - 1);
            const int sa = src_perm[ia];
            const int sb = src_perm[ib];
            u16x8 h0 = *(const u16x8*)(h_bf + (size_t)sa * 256 + c0);
            u16x8 h1 = *(const u16x8*)(h_bf + (size_t)sb * 256 + c0);
            u16x8 e8a = *(const u16x8*)(et + (v0 ? ka : 0) * 264 + c0);
            u16x8 e8b = *(const u16x8*)(et + (v1 ? kb : 0) * 264 + c0);
            const float m0 = v0 ? 1.f : 0.f;
            const float m1 = v1 ? 1.f : 0.f;
#pragma unroll
            for (int j = 0; j < 8; ++j) {
                a[j] += m0 * fmaxf(bf2f((u16)e8a[j]) + bf2f((u16)h0[j]), 0.f);
                a[j] += m1 * fmaxf(bf2f((u16)e8b[j]) + bf2f((u16)h1[j]), 0.f);
            }
        }
    }
#pragma unroll
    for (int j = 0; j < 8; ++j) a[j] += __shfl_xor(a[j], 32);
    if (half == 0) {
        const float c = 1.f + eps[layer];
        u16x8 hbv = *(const u16x8*)(h_bf + (size_t)node * 256 + c0);
        u16x8 z;
#pragma unroll
        for (int j = 0; j < 8; ++j)
            z[j] = f2bf(c * bf2f((u16)hbv[j]) + a[j]);
        *(u16x8*)(z_bf + (size_t)node * 256 + c0) = z;
    }
}

// ---------------- BN + relu + residual (8 elements/thread) ----------------
__global__ __launch_bounds__(256) void bn_res_kernel(
    const u16* __restrict__ y2, const float* __restrict__ colsum,
    const float* __restrict__ colsumsq, const float* __restrict__ gamma,
    const float* __restrict__ beta, const float* __restrict__ hin,
    float* __restrict__ hout, u16* __restrict__ h_bf, int write_bf,
    float invN, int total8) {
    const int i = blockIdx.x * 256 + threadIdx.x;
    if (i >= total8) return;
    const size_t base = (size_t)i * 8;
    const int c0 = (int)(base & 255);
    u16x8 yv = *(const u16x8*)(y2 + base);
    f32x4 hv0 = *(const f32x4*)(hin + base);
    f32x4 hv1 = *(const f32x4*)(hin + base + 4);
    float res[8];
#pragma unroll
    for (int j = 0; j < 8; ++j) {
        const int c = c0 + j;
        const float mu = colsum[c] * invN;
        const float var = colsumsq[c] * invN - mu * mu;
        const float sc = gamma[c] * rsqrtf(var + 1e-5f);
        const float sh = beta[c] - mu * sc;
        float v = bf2f((u16)yv[j]) * sc + sh;
        v = fmaxf(v, 0.f);
        res[j] = ((j < 4) ? hv0[j] : hv1[j - 4]) + v;
    }
    f32x4 o0, o1;
#pragma unroll
    for (int j = 0; j < 4; ++j) { o0[j] = res[j]; o1[j] = res[4 + j]; }
    *(f32x4*)(hout + base) = o0;
    *(f32x4*)(hout + base + 4) = o1;
    if (write_bf) {
        u16x8 hb;
#pragma unroll
        for (int j = 0; j < 8; ++j) hb[j] = f2bf(res[j]);
        *(u16x8*)(h_bf + base) = hb;
    }
}

extern "C" void kernel_launch(void* const* d_in, const int* in_sizes, int n_in,
                              void* d_out, int out_size, void* d_ws, size_t ws_size,
                              hipStream_t stream) {
    const float* x    = (const float*)d_in[0];
    const float* ea   = (const float*)d_in[1];
    const int*   ei   = (const int*)d_in[2];
    const float* Wa   = (const float*)d_in[3];
    const float* ba   = (const float*)d_in[4];
    const float* We   = (const float*)d_in[5];
    const float* be   = (const float*)d_in[6];
    const float* eps  = (const float*)d_in[7];
    const float* W1   = (const float*)d_in[8];
    const float* b1   = (const float*)d_in[9];
    const float* W2   = (const float*)d_in[10];
    const float* b2   = (const float*)d_in[11];
    const float* gamma= (const float*)d_in[12];
    const float* beta = (const float*)d_in[13];

    const int NN = in_sizes[0] / 64;
    const int EE = in_sizes[1] / 16;
    const int* src = ei;
    const int* dst = ei + EE;

    char* p = (char*)d_ws;
    auto alloc = [&](size_t bytes) -> char* {
        char* r = p;
        p += (bytes + 255) & ~(size_t)255;
        return r;
    };
    int*   counts   = (int*)alloc((size_t)(NN + 1) * 4);   // zeroed region start
    float* colsum   = (float*)alloc(5 * 256 * 4);
    float* colsumsq = (float*)alloc(5 * 256 * 4);
    int*   hist     = (int*)alloc(1024 * 4);
    size_t zbytes   = (size_t)(p - (char*)counts);
    int*   hcur     = (int*)alloc(1024 * 4);
    int*   sorted   = (int*)alloc((size_t)NN * 4);
    int*   row_start= (int*)alloc((size_t)(NN + 1) * 4);
    int*   cursor   = (int*)alloc((size_t)NN * 4);
    int*   pos      = (int*)alloc((size_t)EE * 4);
    int*   src_perm = (int*)alloc((size_t)EE * 4);
    u16*   x_bf     = (u16*)alloc((size_t)NN * 64 * 2);
    u16*   Wat      = (u16*)alloc(256 * 64 * 2);
    u16*   Wet      = (u16*)alloc(256 * 32 * 2);
    u16*   W1t      = (u16*)alloc((size_t)5 * 65536 * 2);
    u16*   W2t      = (u16*)alloc((size_t)5 * 65536 * 2);
    u16*   eap_perm = (u16*)alloc((size_t)EE * 32 * 2);
    float* h        = (float*)alloc((size_t)NN * 256 * 4);
    u16*   h_bf     = (u16*)alloc((size_t)NN * 256 * 2);
    u16*   z_bf     = (u16*)alloc((size_t)NN * 256 * 2);
    u16*   y2       = (u16*)alloc((size_t)NN * 256 * 2);

    hipMemsetAsync(counts, 0, zbytes, stream);

    const int eb = (EE + 255) / 256;
    const int nb = (NN + 255) / 256;
    count_kernel<<<eb, 256, 0, stream>>>(dst, EE, counts);
    scan_kernel<<<1, 1024, 0, stream>>>(counts, row_start, cursor, NN);
    pos_kernel<<<eb, 256, 0, stream>>>(src, dst, EE, cursor, pos, src_perm);

    // degree sort (descending) for agg block balance -- two-level, low-contention
    deg_hist_kernel<<<nb, 256, 0, stream>>>(counts, NN, hist);
    scan_hist_kernel<<<1, 1024, 0, stream>>>(hist, hcur);
    sort_fill_kernel<<<nb, 256, 0, stream>>>(counts, NN, hcur, sorted);

    const int prep_total = NN * 16 + 16384 + 8192;
    const int prepb = (prep_total + 255) / 256;
    const int setup_blocks = eb + prepb + 640;
    setup_fused_kernel<<<setup_blocks, 256, 0, stream>>>(
        ea, pos, EE, eb, x, Wa, We, be, NN, prepb, W1, W2,
        eap_perm, x_bf, Wat, Wet, W1t, W2t);

    // h0 = x @ Wa + ba  -> h (f32) and h_bf (bf16)
    dim3 gh((NN + 127) / 128, 2);
    gemm_h0_kernel<<<gh, 256, 0, stream>>>(
        x_bf, 64, NN, Wat, 64, ba, h, h_bf, 256);

    const float invN = 1.f / (float)NN;
    const int nb8 = (NN * 32 + 255) / 256;
    const int mlp_blocks = (NN + 31) / 32;
    for (int l = 0; l < 5; ++l) {
        agg_rc_kernel<<<(NN + 3) / 4, 256, 0, stream>>>(
            sorted, row_start, src_perm, eap_perm, Wet, h_bf, eps, l, z_bf, NN);
        mlp_fused_kernel<<<mlp_blocks, 256, 0, stream>>>(
            z_bf, NN, W1t + (size_t)l * 65536, b1 + l * 256,
            W2t + (size_t)l * 65536, b2 + l * 256, y2,
            colsum + l * 256, colsumsq + l * 256);
        bn_res_kernel<<<nb8, 256, 0, stream>>>(
            y2, colsum + l * 256, colsumsq + l * 256, gamma + l * 256, beta + l * 256,
            h, (l == 4) ? (float*)d_out : h, h_bf, (l < 4) ? 1 : 0, invN, NN * 32);
    }
}